// Round 6
// baseline (61.498 us; speedup 1.0000x reference)
//
#include <hip/hip_runtime.h>
#include <math.h>

// Problem: S=4096, B=16, H=1024
//   energies[b,s] = hidden[b,:] . (W @ enc[s,b,:] + b_attn)
//   out[b,0,s]    = softmax_s(energies[b,s])
// Reassociated: energies[b,s] = v[b,:] . enc[s,b,:] (+ const_b, which cancels
// under softmax shift-invariance), v = hidden @ W.  b_attn never read.
//
// History: coop fusion refuted (R4: scratch spill, 243us). nontemporal
// refuted (R2). R5 = 57.2us with {split-k A1+A2, B PP=4 @4blk/CU, C}.
// R6: merge A1+A2 via atomicAdd (memset 64KB + 1 kernel), B at 8 waves/SIMD.
//   memset v (64 KB)                                  ~0.5 us
//   A : split-k GEMV, atomicAdd -> v (1024 blocks)    ~3 us
//   B : energies, v in 16 VGPRs, 4 pairs/wave, 32 w/CU ~41-44 us (HBM floor)
//   C : per-b softmax in-place on d_out (16 blocks)   ~3 us

#define SS 4096
#define BB 16
#define HH 1024
#define KC 16          // k-chunks for split-k GEMV
#define KLEN (HH / KC) // 64
#define PP 4           // enc rows (pairs) per wave in kernel B

typedef float f4 __attribute__((ext_vector_type(4)));

// ---- A: v[b*HH+h] += sum_{k in chunk kc} hidden[b,k] * W[k,h] -------------
// 1024 blocks x 256 threads. Block -> (kc, b, h-chunk of 256): W reads are
// coalesced over h (1 KB/inst); hidden[b,k] is block-uniform (scalar loads).
// v must be zeroed before this kernel (memsetAsync in kernel_launch).
__global__ void __launch_bounds__(256)
gemv_atomic_kernel(const float* __restrict__ hidden,
                   const float* __restrict__ W,
                   float* __restrict__ v) {
    int blk = blockIdx.x;          // 0..1023
    int kc  = blk >> 6;            // 16 chunks
    int rb  = blk & 63;            // b(16) x hchunk(4)
    int b   = rb >> 2;
    int h   = ((rb & 3) << 8) | threadIdx.x;
    const float* hrow = hidden + b * HH + kc * KLEN;
    const float* Wp   = W + (size_t)(kc * KLEN) * HH + h;
    float a0 = 0.f, a1 = 0.f, a2 = 0.f, a3 = 0.f;
    #pragma unroll 4
    for (int k = 0; k < KLEN; k += 4) {
        a0 += hrow[k + 0] * Wp[(k + 0) * HH];
        a1 += hrow[k + 1] * Wp[(k + 1) * HH];
        a2 += hrow[k + 2] * Wp[(k + 2) * HH];
        a3 += hrow[k + 3] * Wp[(k + 3) * HH];
    }
    atomicAdd(&v[b * HH + h], (a0 + a1) + (a2 + a3));
}

// ---- B: energies[b,s] = v[b,:] . enc[s,b,:] ------------------------------
// One wave per 4 pairs sharing b. v row (4 KB) lives in 16 VGPRs (loaded
// once per wave); each pair is 4x float4 loads (64 lanes x 16 B = 1 KB
// coalesced, 16 enc loads in flight per wave), then 6-step shfl_xor reduces
// and ONE float4 store from lane 0. 8 waves/SIMD (32/CU) for max loads in
// flight -> target full HBM read BW.
__global__ void __launch_bounds__(256, 8)
energies_kernel(const float* __restrict__ enc,
                const float* __restrict__ v,
                float* __restrict__ out) {
    int w    = (blockIdx.x * blockDim.x + threadIdx.x) >> 6;  // wave 0..16383
    int lane = threadIdx.x & 63;
    int b  = w & (BB - 1);
    int sg = w >> 4;               // 0..1023, covers s in [sg*PP, sg*PP+PP)
    const f4* v4 = (const f4*)(v + b * HH);
    f4 vv[4];
    #pragma unroll
    for (int i = 0; i < 4; ++i) vv[i] = v4[i * 64 + lane];
    float acc[PP];
    #pragma unroll
    for (int j = 0; j < PP; ++j) {
        const f4* e4 = (const f4*)(enc + (size_t)((sg * PP + j) * BB + b) * HH);
        f4 a0 = e4[0 * 64 + lane];
        f4 a1 = e4[1 * 64 + lane];
        f4 a2 = e4[2 * 64 + lane];
        f4 a3 = e4[3 * 64 + lane];
        f4 p  = a0 * vv[0] + a1 * vv[1] + a2 * vv[2] + a3 * vv[3];
        acc[j] = (p.x + p.y) + (p.z + p.w);
    }
    #pragma unroll
    for (int j = 0; j < PP; ++j) {
        #pragma unroll
        for (int off = 32; off; off >>= 1) acc[j] += __shfl_xor(acc[j], off, 64);
    }
    if (lane == 0) {
        f4 o;
        o.x = acc[0]; o.y = acc[1]; o.z = acc[2]; o.w = acc[3];
        *(f4*)(out + b * SS + sg * PP) = o;
    }
}

// ---- C: in-place softmax over s, one 256-thread block per b --------------
__global__ void __launch_bounds__(256)
softmax_kernel(float* __restrict__ out) {
    int b = blockIdx.x;
    float* row = out + b * SS;
    int t = threadIdx.x;                 // 16 values per thread
    float vals[16];
    float m = -INFINITY;
    #pragma unroll
    for (int i = 0; i < 16; ++i) {
        vals[i] = row[t + i * 256];
        m = fmaxf(m, vals[i]);
    }
    #pragma unroll
    for (int off = 32; off; off >>= 1) m = fmaxf(m, __shfl_xor(m, off, 64));
    __shared__ float redm[4];
    __shared__ float reds[4];
    int wid = t >> 6;
    if ((t & 63) == 0) redm[wid] = m;
    __syncthreads();
    m = fmaxf(fmaxf(redm[0], redm[1]), fmaxf(redm[2], redm[3]));

    float sum = 0.f;
    #pragma unroll
    for (int i = 0; i < 16; ++i) {
        vals[i] = expf(vals[i] - m);
        sum += vals[i];
    }
    #pragma unroll
    for (int off = 32; off; off >>= 1) sum += __shfl_xor(sum, off, 64);
    if ((t & 63) == 0) reds[wid] = sum;
    __syncthreads();
    sum = reds[0] + reds[1] + reds[2] + reds[3];
    float inv = 1.0f / sum;
    #pragma unroll
    for (int i = 0; i < 16; ++i) row[t + i * 256] = vals[i] * inv;
}

extern "C" void kernel_launch(void* const* d_in, const int* in_sizes, int n_in,
                              void* d_out, int out_size, void* d_ws, size_t ws_size,
                              hipStream_t stream) {
    const float* hidden = (const float*)d_in[0];   // [1,B,H]
    const float* enc    = (const float*)d_in[1];   // [S,B,H]
    const float* W      = (const float*)d_in[2];   // [H,H]
    // d_in[3] = b_attn: cancels in softmax (and is zero in setup_inputs)
    float* out = (float*)d_out;                    // [B,1,S]
    float* v   = (float*)d_ws;                     // B*H floats = 64 KB

    hipMemsetAsync(v, 0, BB * HH * sizeof(float), stream);
    hipLaunchKernelGGL(gemv_atomic_kernel, dim3(KC * 64), dim3(256), 0, stream,
                       hidden, W, v);
    hipLaunchKernelGGL(energies_kernel, dim3(SS * BB / PP / 4), dim3(256), 0, stream,
                       enc, v, out);
    hipLaunchKernelGGL(softmax_kernel, dim3(BB), dim3(256), 0, stream, out);
}

// Round 7
// 56.693 us; speedup vs baseline: 1.0848x; 1.0848x over previous
//
#include <hip/hip_runtime.h>
#include <math.h>

// Problem: S=4096, B=16, H=1024
//   energies[b,s] = hidden[b,:] . (W @ enc[s,b,:] + b_attn)
//   out[b,0,s]    = softmax_s(energies[b,s])
// Reassociated: energies[b,s] = v[b,:] . enc[s,b,:] (+ const_b, which cancels
// under softmax shift-invariance), v = hidden @ W.  b_attn never read.
//
// History: coop fusion refuted (R4, scratch spill). nontemporal refuted (R2).
// B @ 8 waves/SIMD refuted (R6: 64-VGPR cap serialized loads, 61.5us).
// Best known: R5 = 57.2us {A1 split-k, A2 reduce, B PP=4 @(256,4), C}.
// R7: B restructured to persistent blocks + CONTIGUOUS streaming + v in LDS.
//   enc == 256 MiB == L3 size; R4 counters showed ~47% L3 hit across replays.

#define SS 4096
#define BB 16
#define HH 1024
#define KC 16          // k-chunks for split-k GEMV
#define KLEN (HH / KC) // 64

#define BNB 512        // kernel B: blocks (2 per CU)
#define BNT 512        // kernel B: threads per block (8 waves)
#define NGRP (SS * BB / 32)   // 2048 groups of 32 consecutive pairs
#define TILES (NGRP / BNB)    // 4 groups per block

typedef float f4 __attribute__((ext_vector_type(4)));

// ---- A1: partial[kc][b*HH+h] = sum_{k in chunk kc} hidden[b,k] * W[k,h] ----
// (unchanged from R5) 1024 blocks x 256 threads; W reads coalesced over h.
__global__ void __launch_bounds__(256)
gemv_partial_kernel(const float* __restrict__ hidden,
                    const float* __restrict__ W,
                    float* __restrict__ partial) {
    int blk = blockIdx.x;          // 0..1023
    int kc  = blk >> 6;            // 16 chunks
    int rb  = blk & 63;            // b(16) x hchunk(4)
    int b   = rb >> 2;
    int h   = ((rb & 3) << 8) | threadIdx.x;
    const float* hrow = hidden + b * HH + kc * KLEN;
    const float* Wp   = W + (size_t)(kc * KLEN) * HH + h;
    float a0 = 0.f, a1 = 0.f, a2 = 0.f, a3 = 0.f;
    #pragma unroll 4
    for (int k = 0; k < KLEN; k += 4) {
        a0 += hrow[k + 0] * Wp[(k + 0) * HH];
        a1 += hrow[k + 1] * Wp[(k + 1) * HH];
        a2 += hrow[k + 2] * Wp[(k + 2) * HH];
        a3 += hrow[k + 3] * Wp[(k + 3) * HH];
    }
    partial[kc * (BB * HH) + b * HH + h] = (a0 + a1) + (a2 + a3);
}

// ---- A2: v[i] = sum_kc partial[kc][i] (unchanged from R5) -----------------
__global__ void __launch_bounds__(256)
gemv_reduce_kernel(const float* __restrict__ partial,
                   float* __restrict__ v) {
    int i = blockIdx.x * 256 + threadIdx.x;   // 0..16383
    float s = 0.f;
    #pragma unroll
    for (int kc = 0; kc < KC; ++kc) s += partial[kc * (BB * HH) + i];
    v[i] = s;
}

// ---- B: energies[b,s] = v[b,:] . enc[s,b,:]  (persistent + contiguous) ----
// 512 blocks x 512 threads, 2 blocks/CU (LDS 64 KB/block). Each block stages
// the whole v (64 KB) into LDS once, then sweeps TILES=4 groups of 32
// CONSECUTIVE pairs p = s*16+b; wave i takes pairs p0=g*32+i*4..+3, i.e. one
// contiguous 16 KB span of enc per wave per tile (DRAM/L3-friendly frontier,
// all 512 blocks in phase). vv comes from LDS per pair (conflict-free
// consecutive-lane ds_read_b128). Butterfly-reduce, lane0 writes 4 floats.
__global__ void __launch_bounds__(BNT, 4)
energies_kernel(const float* __restrict__ enc,
                const float* __restrict__ v,
                float* __restrict__ out) {
    __shared__ f4 vlds[BB * HH / 4];        // 4096 f4 = 64 KB
    int tid = threadIdx.x;
    const f4* vg = (const f4*)v;
    #pragma unroll
    for (int it = 0; it < (BB * HH / 4) / BNT; ++it)   // 8 iters
        vlds[it * BNT + tid] = vg[it * BNT + tid];
    __syncthreads();

    int lane = tid & 63;
    int wi   = tid >> 6;                    // wave in block, 0..7
    for (int t = 0; t < TILES; ++t) {
        int g  = t * BNB + blockIdx.x;      // group 0..2047
        int p0 = g * 32 + wi * 4;           // first of 4 consecutive pairs
        float acc[4];
        #pragma unroll
        for (int j = 0; j < 4; ++j) {
            int p = p0 + j;
            int b = p & (BB - 1);
            const f4* e4 = (const f4*)(enc + (size_t)p * HH);
            f4 a0 = e4[0 * 64 + lane];
            f4 a1 = e4[1 * 64 + lane];
            f4 a2 = e4[2 * 64 + lane];
            f4 a3 = e4[3 * 64 + lane];
            f4 w0 = vlds[b * 256 + 0 * 64 + lane];
            f4 w1 = vlds[b * 256 + 1 * 64 + lane];
            f4 w2 = vlds[b * 256 + 2 * 64 + lane];
            f4 w3 = vlds[b * 256 + 3 * 64 + lane];
            f4 pr = a0 * w0 + a1 * w1 + a2 * w2 + a3 * w3;
            acc[j] = (pr.x + pr.y) + (pr.z + pr.w);
        }
        #pragma unroll
        for (int j = 0; j < 4; ++j) {
            #pragma unroll
            for (int off = 32; off; off >>= 1)
                acc[j] += __shfl_xor(acc[j], off, 64);
        }
        if (lane == 0) {
            #pragma unroll
            for (int j = 0; j < 4; ++j) {
                int p = p0 + j;
                out[(p & (BB - 1)) * SS + (p >> 4)] = acc[j];
            }
        }
    }
}

// ---- C: in-place softmax over s, one 256-thread block per b (unchanged) ---
__global__ void __launch_bounds__(256)
softmax_kernel(float* __restrict__ out) {
    int b = blockIdx.x;
    float* row = out + b * SS;
    int t = threadIdx.x;                 // 16 values per thread
    float vals[16];
    float m = -INFINITY;
    #pragma unroll
    for (int i = 0; i < 16; ++i) {
        vals[i] = row[t + i * 256];
        m = fmaxf(m, vals[i]);
    }
    #pragma unroll
    for (int off = 32; off; off >>= 1) m = fmaxf(m, __shfl_xor(m, off, 64));
    __shared__ float redm[4];
    __shared__ float reds[4];
    int wid = t >> 6;
    if ((t & 63) == 0) redm[wid] = m;
    __syncthreads();
    m = fmaxf(fmaxf(redm[0], redm[1]), fmaxf(redm[2], redm[3]));

    float sum = 0.f;
    #pragma unroll
    for (int i = 0; i < 16; ++i) {
        vals[i] = expf(vals[i] - m);
        sum += vals[i];
    }
    #pragma unroll
    for (int off = 32; off; off >>= 1) sum += __shfl_xor(sum, off, 64);
    if ((t & 63) == 0) reds[wid] = sum;
    __syncthreads();
    sum = reds[0] + reds[1] + reds[2] + reds[3];
    float inv = 1.0f / sum;
    #pragma unroll
    for (int i = 0; i < 16; ++i) row[t + i * 256] = vals[i] * inv;
}

extern "C" void kernel_launch(void* const* d_in, const int* in_sizes, int n_in,
                              void* d_out, int out_size, void* d_ws, size_t ws_size,
                              hipStream_t stream) {
    const float* hidden = (const float*)d_in[0];   // [1,B,H]
    const float* enc    = (const float*)d_in[1];   // [S,B,H]
    const float* W      = (const float*)d_in[2];   // [H,H]
    // d_in[3] = b_attn: cancels in softmax (and is zero in setup_inputs)
    float* out     = (float*)d_out;                // [B,1,S]
    float* v       = (float*)d_ws;                 // B*H floats    = 64 KB
    float* partial = v + BB * HH;                  // KC*B*H floats = 1 MB

    hipLaunchKernelGGL(gemv_partial_kernel, dim3(KC * 64), dim3(256), 0, stream,
                       hidden, W, partial);
    hipLaunchKernelGGL(gemv_reduce_kernel, dim3(BB * HH / 256), dim3(256), 0, stream,
                       partial, v);
    hipLaunchKernelGGL(energies_kernel, dim3(BNB), dim3(BNT), 0, stream,
                       enc, v, out);
    hipLaunchKernelGGL(softmax_kernel, dim3(BB), dim3(256), 0, stream, out);
}